// Round 5
// baseline (260.130 us; speedup 1.0000x reference)
//
#include <hip/hip_runtime.h>
#include <hip/hip_bf16.h>
#include <stdint.h>

#define N_NODES 6144
#define IN_F    512
#define OUT_F   64
#define NH      8
#define ALPHA   0.2f
#define L2E     1.4426950408889634f
#define NTILES  (N_NODES / 64)   // 96

typedef __attribute__((ext_vector_type(8))) short bf16x8;
typedef __attribute__((ext_vector_type(4))) float f32x4;

#define MFMA16(a, b, c) __builtin_amdgcn_mfma_f32_16x16x32_bf16(a, b, c, 0, 0, 0)

__device__ __forceinline__ unsigned short f2bf(float f) {
    uint32_t u = __float_as_uint(f);
    u += 0x7fffu + ((u >> 16) & 1u);     // round-to-nearest-even
    return (unsigned short)(u >> 16);
}
__device__ __forceinline__ float bf2f(unsigned short h) {
    return __uint_as_float(((uint32_t)h) << 16);
}

// ---------------------------------------------------------------------------
// x (f32 [N, 512]) -> xh (bf16 hi) + xl (bf16 of residual), same layout
__global__ __launch_bounds__(256) void k_convert_x(
    const float* __restrict__ x, unsigned short* __restrict__ xh,
    unsigned short* __restrict__ xl)
{
    int i = blockIdx.x * 256 + threadIdx.x;          // per float4, 786432 total
    float4 v = ((const float4*)x)[i];
    float vv[4] = {v.x, v.y, v.z, v.w};
    unsigned short h4[4], l4[4];
#pragma unroll
    for (int c = 0; c < 4; ++c) {
        unsigned short hb = f2bf(vv[c]);
        h4[c] = hb;
        l4[c] = f2bf(vv[c] - bf2f(hb));
    }
    ((ushort4*)xh)[i] = make_ushort4(h4[0], h4[1], h4[2], h4[3]);
    ((ushort4*)xl)[i] = make_ushort4(l4[0], l4[1], l4[2], l4[3]);
}

// ---------------------------------------------------------------------------
// W (f32 [8, 512, 64]) -> WT (bf16 [col=h*64+f][k=512]) hi + lo
__global__ __launch_bounds__(256) void k_convert_w(
    const float* __restrict__ W, unsigned short* __restrict__ wth,
    unsigned short* __restrict__ wtl)
{
    int tid = blockIdx.x * 256 + threadIdx.x;        // 262144
    int col = tid >> 9, k = tid & 511;
    int h = col >> 6, f = col & 63;
    float wv = W[(h * IN_F + k) * OUT_F + f];
    unsigned short hb = f2bf(wv);
    wth[tid] = hb;                                    // tid == col*512 + k
    wtl[tid] = f2bf(wv - bf2f(hb));
}

// ---------------------------------------------------------------------------
// adj (int32 [N,N]) -> bitmask u64 [N][N/64], grid-stride
__global__ __launch_bounds__(256) void k_pack_adj(
    const int* __restrict__ adj, unsigned long long* __restrict__ bm)
{
    const int stride = gridDim.x * 256;
    for (int idx = blockIdx.x * 256 + threadIdx.x; idx < N_NODES * N_NODES;
         idx += stride) {
        unsigned long long b = __ballot(adj[idx] > 0);
        if ((threadIdx.x & 63) == 0) bm[idx >> 6] = b;
    }
}

// ---------------------------------------------------------------------------
// Projection: h = x @ W per head via split-bf16 MFMA (xh@Wh + xh@Wl + xl@Wh).
__global__ __launch_bounds__(256) void k_proj(
    const unsigned short* __restrict__ xh, const unsigned short* __restrict__ xl,
    const unsigned short* __restrict__ wth, const unsigned short* __restrict__ wtl,
    const float* __restrict__ a1, const float* __restrict__ a2,
    unsigned short* __restrict__ hT, float* __restrict__ s1,
    float* __restrict__ s2)
{
    const int head = blockIdx.x & 7;
    const int rb = blockIdx.x >> 3;                  // 0..95
    const int w = threadIdx.x >> 6;
    const int lane = threadIdx.x & 63;
    const int r15 = lane & 15;
    const int g = lane >> 4;
    const int rowbase = rb * 64 + w * 16;
    const int rowA = rowbase + r15;

    f32x4 acc[4] = {};
    const unsigned short* xhp = xh + (size_t)rowA * IN_F + g * 8;
    const unsigned short* xlp = xl + (size_t)rowA * IN_F + g * 8;
    const int colbase = head * 64;

#pragma unroll 4
    for (int i = 0; i < 16; ++i) {
        const int k0 = i * 32;
        bf16x8 ah = *(const bf16x8*)(xhp + k0);
        bf16x8 al = *(const bf16x8*)(xlp + k0);
#pragma unroll
        for (int ct = 0; ct < 4; ++ct) {
            size_t boff = (size_t)(colbase + ct * 16 + r15) * IN_F + k0 + g * 8;
            bf16x8 bh = *(const bf16x8*)(wth + boff);
            bf16x8 bl = *(const bf16x8*)(wtl + boff);
            acc[ct] = MFMA16(ah, bh, acc[ct]);
            acc[ct] = MFMA16(ah, bl, acc[ct]);
            acc[ct] = MFMA16(al, bh, acc[ct]);
        }
    }

    float a1v[4], a2v[4];
#pragma unroll
    for (int ct = 0; ct < 4; ++ct) {
        a1v[ct] = a1[head * 64 + ct * 16 + r15];
        a2v[ct] = a2[head * 64 + ct * 16 + r15];
    }
    float sp1[4] = {0, 0, 0, 0}, sp2[4] = {0, 0, 0, 0};
#pragma unroll
    for (int ct = 0; ct < 4; ++ct)
#pragma unroll
        for (int j = 0; j < 4; ++j) {
            sp1[j] += acc[ct][j] * a1v[ct];
            sp2[j] += acc[ct][j] * a2v[ct];
        }
#pragma unroll
    for (int d = 1; d < 16; d <<= 1) {
#pragma unroll
        for (int j = 0; j < 4; ++j) {
            sp1[j] += __shfl_xor(sp1[j], d);
            sp2[j] += __shfl_xor(sp2[j], d);
        }
    }
    if (r15 == 0) {
#pragma unroll
        for (int j = 0; j < 4; ++j) {
            int n = rowbase + g * 4 + j;
            s1[head * N_NODES + n] = sp1[j];
            s2[head * N_NODES + n] = sp2[j];
        }
    }
#pragma unroll
    for (int ct = 0; ct < 4; ++ct) {
        ushort4 pk;
        pk.x = f2bf(acc[ct][0]);
        pk.y = f2bf(acc[ct][1]);
        pk.z = f2bf(acc[ct][2]);
        pk.w = f2bf(acc[ct][3]);
        int fcol = head * 64 + ct * 16 + r15;
        int n0 = rowbase + g * 4;
        *(ushort4*)(hT + (size_t)fcol * N_NODES + n0) = pk;
    }
}

// ---------------------------------------------------------------------------
// per-head max of s2 (unmasked upper bound for softmax stabilization)
__global__ __launch_bounds__(256) void k_s2max(
    const float* __restrict__ s2, float* __restrict__ s2m)
{
    const int h = blockIdx.x;
    float m = -3.0e38f;
    for (int i = threadIdx.x; i < N_NODES; i += 256)
        m = fmaxf(m, s2[h * N_NODES + i]);
#pragma unroll
    for (int d = 1; d < 64; d <<= 1) m = fmaxf(m, __shfl_xor(m, d));
    __shared__ float wm[4];
    if ((threadIdx.x & 63) == 0) wm[threadIdx.x >> 6] = m;
    __syncthreads();
    if (threadIdx.x == 0)
        s2m[h] = fmaxf(fmaxf(wm[0], wm[1]), fmaxf(wm[2], wm[3]));
}

// ---------------------------------------------------------------------------
// tables pre-scaled by s2max so every factor <= 1 (no overflow possible):
//   e2p = exp(s2 - s2m), e2n = exp(alpha*(s2 - s2m))
__global__ __launch_bounds__(256) void k_tables(
    const float* __restrict__ s2, const float* __restrict__ s2m,
    float* __restrict__ e2p, float* __restrict__ e2n)
{
    int i = blockIdx.x * 256 + threadIdx.x;          // H*N
    int h = i / N_NODES;
    float v = s2[i] - s2m[h];
    e2p[i] = exp2f(v * L2E);
    e2n[i] = exp2f(ALPHA * v * L2E);
}

// ---------------------------------------------------------------------------
// P-fragment builder: p = max(E1p*e2p[m], E1n*e2n[m]) masked by adjacency.
// msel must hold this lane-group's 8 mask bits in bits 0..7.
__device__ __forceinline__ bf16x8 mk_pa(float4 ea, float4 eb, float4 na,
                                        float4 nb, float e1p, float e1n,
                                        uint32_t msel)
{
    float ep[8] = {ea.x, ea.y, ea.z, ea.w, eb.x, eb.y, eb.z, eb.w};
    float en[8] = {na.x, na.y, na.z, na.w, nb.x, nb.y, nb.z, nb.w};
    uint32_t pk[4];
#define PAIR(J2, B0, B1)                                                      \
    {                                                                         \
        float p0 = fmaxf(e1p * ep[2 * J2],     e1n * en[2 * J2]);             \
        float p1 = fmaxf(e1p * ep[2 * J2 + 1], e1n * en[2 * J2 + 1]);         \
        int mb0, mb1;                                                         \
        asm("v_bfe_i32 %0, %1, " #B0 ", 1" : "=v"(mb0) : "v"(msel));          \
        asm("v_bfe_i32 %0, %1, " #B1 ", 1" : "=v"(mb1) : "v"(msel));          \
        p0 = __uint_as_float(__float_as_uint(p0) & (uint32_t)mb0);            \
        p1 = __uint_as_float(__float_as_uint(p1) & (uint32_t)mb1);            \
        asm("v_cvt_pk_bf16_f32 %0, %1, %2" : "=v"(pk[J2]) : "v"(p0), "v"(p1));\
    }
    PAIR(0, 0, 1)
    PAIR(1, 2, 3)
    PAIR(2, 4, 5)
    PAIR(3, 6, 7)
#undef PAIR
    union { uint32_t u[4]; bf16x8 v; } pun;
    pun.u[0] = pk[0]; pun.u[1] = pk[1]; pun.u[2] = pk[2]; pun.u[3] = pk[3];
    return pun.v;
}

struct Pf {                          // one-tile-ahead register prefetch
    float4 ea, eb, na, nb;           // tables for this wave's m-half
    uint32_t m0, m1;                 // adjacency mask words per row-group
};

// ---------------------------------------------------------------------------
// Flash attention v4b: 256 threads (4 waves), 64 rows/block. Wave = (row-half
// w01, m-half wk). Same total work as v3 but 12 waves/CU -> latency hiding.
// Partial accumulators combined through LDS in the epilogue.
// FIX vs v4: per-lane-group mask shift (>> g*8) restored at mk_pa call sites.
__global__ __launch_bounds__(256, 3) void k_flash(
    const unsigned short* __restrict__ hT, const float* __restrict__ s1,
    const float* __restrict__ s2m, const float* __restrict__ e2p,
    const float* __restrict__ e2n, const unsigned long long* __restrict__ bm,
    float* __restrict__ out)
{
    __shared__ unsigned short sht[2][64][64];        // 16 KB, XOR-swizzled

    const int head = blockIdx.x / NTILES;
    const int rb = blockIdx.x % NTILES;
    const int tid = threadIdx.x;
    const int w = tid >> 6, lane = tid & 63, r15 = lane & 15, g = lane >> 4;
    const int r7 = r15 & 7;
    const int w01 = w & 1;                           // row half
    const int wk = w >> 1;                           // m half (kk)
    const int shg = g * 8;                           // mask bit offset

    const int rA = rb * 64 + w01 * 32 + r15;
    const int rB = rA + 16;
    const float s2mh = s2m[head];
    const float s1A = s1[head * N_NODES + rA];
    const float s1B = s1[head * N_NODES + rB];
    const float t0A = s1A + s2mh, t0B = s1B + s2mh;
    const float MrA = fmaxf(t0A, ALPHA * t0A);
    const float MrB = fmaxf(t0B, ALPHA * t0B);
    const float E1pA = exp2f((t0A - MrA) * L2E);
    const float E1nA = exp2f((ALPHA * t0A - MrA) * L2E);
    const float E1pB = exp2f((t0B - MrB) * L2E);
    const float E1nB = exp2f((ALPHA * t0B - MrB) * L2E);

    const float* __restrict__ e2ph = e2p + head * N_NODES;
    const float* __restrict__ e2nh = e2n + head * N_NODES;
    const unsigned short* __restrict__ hTh = hT + (size_t)head * 64 * N_NODES;
    const uint32_t* __restrict__ bm32 = (const uint32_t*)bm;
    const size_t bmA = (size_t)rA * NTILES * 2 + wk;
    const size_t bmB = (size_t)rB * NTILES * 2 + wk;

    f32x4 accA[4] = {}, accB[4] = {};
    f32x4 accSA = {}, accSB = {};
    const bf16x8 vones = {(short)0x3F80, (short)0x3F80, (short)0x3F80,
                          (short)0x3F80, (short)0x3F80, (short)0x3F80,
                          (short)0x3F80, (short)0x3F80};

    // staging geometry: 256 threads x 2 int4 = 8 KB tile
    const int fr = tid >> 3;                          // 0..31
    const int cc = tid & 7;
    const int wcol = ((cc ^ (fr & 7)) << 3);          // swizzled col (shorts)
    // read-side swizzled chunk for this wave's m-half
    const int rcol = (((wk * 4 + g) ^ r7) << 3);
    const int tblofs = wk * 32 + g * 8;

    {   // prologue: stage tile 0 directly
        int4 v0 = *(const int4*)(hTh + (size_t)fr * N_NODES + cc * 8);
        int4 v1 = *(const int4*)(hTh + (size_t)(fr + 32) * N_NODES + cc * 8);
        *(int4*)&sht[0][fr][wcol] = v0;
        *(int4*)&sht[0][fr + 32][wcol] = v1;
    }
    Pf A, B;
    {   // prologue: prefetch tile-0 tables + masks
        A.m0 = bm32[bmA];
        A.m1 = bm32[bmB];
        A.ea = *(const float4*)(e2ph + tblofs);
        A.eb = *(const float4*)(e2ph + tblofs + 4);
        A.na = *(const float4*)(e2nh + tblofs);
        A.nb = *(const float4*)(e2nh + tblofs + 4);
    }
    __syncthreads();

    auto body = [&](int t, Pf& C, Pf& Nx) {
        const int cur = t & 1;
        const int tn = (t + 1 < NTILES) ? (t + 1) : (NTILES - 1);
        // prefetch next tile: staging (local regs), masks + tables (into Nx)
        int4 st0, st1;
        {
            const int m0n = tn * 64 + cc * 8;
            st0 = *(const int4*)(hTh + (size_t)fr * N_NODES + m0n);
            st1 = *(const int4*)(hTh + (size_t)(fr + 32) * N_NODES + m0n);
            Nx.m0 = bm32[bmA + (size_t)tn * 2];
            Nx.m1 = bm32[bmB + (size_t)tn * 2];
            const int mb0 = tn * 64 + tblofs;
            Nx.ea = *(const float4*)(e2ph + mb0);
            Nx.eb = *(const float4*)(e2ph + mb0 + 4);
            Nx.na = *(const float4*)(e2nh + mb0);
            Nx.nb = *(const float4*)(e2nh + mb0 + 4);
        }
        const unsigned short(*buf)[64] = sht[cur];

        bf16x8 paA = mk_pa(C.ea, C.eb, C.na, C.nb, E1pA, E1nA, C.m0 >> shg);
        bf16x8 paB = mk_pa(C.ea, C.eb, C.na, C.nb, E1pB, E1nB, C.m1 >> shg);
        accSA = MFMA16(paA, vones, accSA);
        accSB = MFMA16(paB, vones, accSB);
#pragma unroll
        for (int ct = 0; ct < 4; ++ct) {
            bf16x8 hb = *(const bf16x8*)&buf[ct * 16 + r15][rcol];
            accA[ct] = MFMA16(paA, hb, accA[ct]);
            accB[ct] = MFMA16(paB, hb, accB[ct]);
        }

        // write next tile into other buffer, single barrier
        const int bufn = cur ^ 1;
        *(int4*)&sht[bufn][fr][wcol] = st0;
        *(int4*)&sht[bufn][fr + 32][wcol] = st1;
        __syncthreads();
    };

    for (int t = 0; t < NTILES; t += 2) {
        body(t, A, B);
        body(t + 1, B, A);
    }

    // ---- epilogue: combine the two m-half waves through LDS ----
    float* fs = (float*)sht;                          // reuse 16 KB scratch
    const int slot = w01 * 64 + lane;
    const int fcb = head * 64;
    const int nA = rb * 64 + w01 * 32 + g * 4;

    // phase 1: row-group A
    if (wk == 1) {
#pragma unroll
        for (int ct = 0; ct < 4; ++ct)
#pragma unroll
            for (int j = 0; j < 4; ++j) fs[slot * 20 + ct * 4 + j] = accA[ct][j];
#pragma unroll
        for (int j = 0; j < 4; ++j) fs[slot * 20 + 16 + j] = accSA[j];
    }
    __syncthreads();
    if (wk == 0) {
        float rinv[4];
#pragma unroll
        for (int j = 0; j < 4; ++j)
            rinv[j] = 1.0f / (accSA[j] + fs[slot * 20 + 16 + j]);
#pragma unroll
        for (int ct = 0; ct < 4; ++ct)
#pragma unroll
            for (int j = 0; j < 4; ++j) {
                float v = (accA[ct][j] + fs[slot * 20 + ct * 4 + j]) * rinv[j];
                v = (v > 0.f) ? v : (expf(v) - 1.f);
                out[(size_t)(nA + j) * 512 + fcb + ct * 16 + r15] = v;
            }
    }
    __syncthreads();
    // phase 2: row-group B
    if (wk == 1) {
#pragma unroll
        for (int ct = 0; ct < 4; ++ct)
#pragma unroll
            for (int j = 0; j < 4; ++j) fs[slot * 20 + ct * 4 + j] = accB[ct][j];
#pragma unroll
        for (int j = 0; j < 4; ++j) fs[slot * 20 + 16 + j] = accSB[j];
    }
    __syncthreads();
    if (wk == 0) {
        float rinv[4];
#pragma unroll
        for (int j = 0; j < 4; ++j)
            rinv[j] = 1.0f / (accSB[j] + fs[slot * 20 + 16 + j]);
#pragma unroll
        for (int ct = 0; ct < 4; ++ct)
#pragma unroll
            for (int j = 0; j < 4; ++j) {
                float v = (accB[ct][j] + fs[slot * 20 + ct * 4 + j]) * rinv[j];
                v = (v > 0.f) ? v : (expf(v) - 1.f);
                out[(size_t)(nA + 16 + j) * 512 + fcb + ct * 16 + r15] = v;
            }
    }
}

// ---------------------------------------------------------------------------
extern "C" void kernel_launch(void* const* d_in, const int* in_sizes, int n_in,
                              void* d_out, int out_size, void* d_ws, size_t ws_size,
                              hipStream_t stream)
{
    const float* x = (const float*)d_in[0];
    const int* adj = (const int*)d_in[1];
    const float* W = (const float*)d_in[2];
    const float* a1 = (const float*)d_in[3];
    const float* a2 = (const float*)d_in[4];
    float* out = (float*)d_out;

    char* ws = (char*)d_ws;
    size_t off = 0;
    auto take = [&](size_t bytes) {
        void* p = ws + off;
        off = (off + bytes + 255) & ~(size_t)255;
        return p;
    };
    unsigned short* xh  = (unsigned short*)take((size_t)N_NODES * IN_F * 2);
    unsigned short* xl  = (unsigned short*)take((size_t)N_NODES * IN_F * 2);
    unsigned short* wth = (unsigned short*)take((size_t)512 * 512 * 2);
    unsigned short* wtl = (unsigned short*)take((size_t)512 * 512 * 2);
    unsigned short* hT  = (unsigned short*)take((size_t)NH * 64 * N_NODES * 2);
    float* s1  = (float*)take((size_t)NH * N_NODES * 4);
    float* s2  = (float*)take((size_t)NH * N_NODES * 4);
    float* s2m = (float*)take(256);
    float* e2p = (float*)take((size_t)NH * N_NODES * 4);
    float* e2n = (float*)take((size_t)NH * N_NODES * 4);
    unsigned long long* bmask =
        (unsigned long long*)take((size_t)N_NODES * (N_NODES / 64) * 8);

    k_convert_x<<<dim3((N_NODES * IN_F / 4) / 256), dim3(256), 0, stream>>>(x, xh, xl);
    k_convert_w<<<dim3((512 * 512) / 256), dim3(256), 0, stream>>>(W, wth, wtl);
    k_pack_adj<<<dim3(2048), dim3(256), 0, stream>>>(adj, bmask);
    k_proj<<<dim3(NH * (N_NODES / 64)), dim3(256), 0, stream>>>(
        xh, xl, wth, wtl, a1, a2, hT, s1, s2);
    k_s2max<<<dim3(NH), dim3(256), 0, stream>>>(s2, s2m);
    k_tables<<<dim3(NH * N_NODES / 256), dim3(256), 0, stream>>>(s2, s2m, e2p, e2n);
    k_flash<<<dim3(NH * NTILES), dim3(256), 0, stream>>>(
        hT, s1, s2m, e2p, e2n, bmask, out);
}

// Round 6
// 195.535 us; speedup vs baseline: 1.3304x; 1.3304x over previous
//
#include <hip/hip_runtime.h>
#include <hip/hip_bf16.h>
#include <stdint.h>

#define N_NODES 6144
#define IN_F    512
#define OUT_F   64
#define NH      8
#define ALPHA   0.2f
#define L2E     1.4426950408889634f
#define NTILES  (N_NODES / 64)   // 96

typedef __attribute__((ext_vector_type(8))) short bf16x8;
typedef __attribute__((ext_vector_type(8))) _Float16 f16x8;
typedef __attribute__((ext_vector_type(4))) float f32x4;

#define MFMA16B(a, b, c) __builtin_amdgcn_mfma_f32_16x16x32_bf16(a, b, c, 0, 0, 0)
#define MFMA16H(a, b, c) __builtin_amdgcn_mfma_f32_16x16x32_f16(a, b, c, 0, 0, 0)

__device__ __forceinline__ unsigned short f2bf(float f) {
    uint32_t u = __float_as_uint(f);
    u += 0x7fffu + ((u >> 16) & 1u);     // round-to-nearest-even
    return (unsigned short)(u >> 16);
}
__device__ __forceinline__ float bf2f(unsigned short h) {
    return __uint_as_float(((uint32_t)h) << 16);
}
__device__ __forceinline__ uint32_t f16bits(_Float16 h) {
    union { _Float16 h; unsigned short u; } c;
    c.h = h;
    return (uint32_t)c.u;
}

// ---------------------------------------------------------------------------
// x (f32 [N, 512]) -> xh (bf16 hi) + xl (bf16 of residual), same layout
__global__ __launch_bounds__(256) void k_convert_x(
    const float* __restrict__ x, unsigned short* __restrict__ xh,
    unsigned short* __restrict__ xl)
{
    int i = blockIdx.x * 256 + threadIdx.x;          // per float4, 786432 total
    float4 v = ((const float4*)x)[i];
    float vv[4] = {v.x, v.y, v.z, v.w};
    unsigned short h4[4], l4[4];
#pragma unroll
    for (int c = 0; c < 4; ++c) {
        unsigned short hb = f2bf(vv[c]);
        h4[c] = hb;
        l4[c] = f2bf(vv[c] - bf2f(hb));
    }
    ((ushort4*)xh)[i] = make_ushort4(h4[0], h4[1], h4[2], h4[3]);
    ((ushort4*)xl)[i] = make_ushort4(l4[0], l4[1], l4[2], l4[3]);
}

// ---------------------------------------------------------------------------
// W (f32 [8, 512, 64]) -> WT (bf16 [col=h*64+f][k=512]) hi + lo
__global__ __launch_bounds__(256) void k_convert_w(
    const float* __restrict__ W, unsigned short* __restrict__ wth,
    unsigned short* __restrict__ wtl)
{
    int tid = blockIdx.x * 256 + threadIdx.x;        // 262144
    int col = tid >> 9, k = tid & 511;
    int h = col >> 6, f = col & 63;
    float wv = W[(h * IN_F + k) * OUT_F + f];
    unsigned short hb = f2bf(wv);
    wth[tid] = hb;                                    // tid == col*512 + k
    wtl[tid] = f2bf(wv - bf2f(hb));
}

// ---------------------------------------------------------------------------
// adj (int32 [N,N]) -> TRANSPOSED bitmask u32 view: bmT[tile_cb][row] (u64),
// so per-tile mask reads are coalesced across rows.
__global__ __launch_bounds__(256) void k_pack_adj(
    const int* __restrict__ adj, unsigned long long* __restrict__ bmT)
{
    const int stride = gridDim.x * 256;
    for (int idx = blockIdx.x * 256 + threadIdx.x; idx < N_NODES * N_NODES;
         idx += stride) {
        unsigned long long b = __ballot(adj[idx] > 0);
        if ((threadIdx.x & 63) == 0) {
            int r = idx / N_NODES;
            int cb = (idx % N_NODES) >> 6;
            bmT[(size_t)cb * N_NODES + r] = b;
        }
    }
}

// ---------------------------------------------------------------------------
// Projection: h = x @ W per head via split-bf16 MFMA (xh@Wh + xh@Wl + xl@Wh).
// Writes hT (bf16 [h][f][n]) and s1/s2 (f32 [h][n]).
__global__ __launch_bounds__(256) void k_proj(
    const unsigned short* __restrict__ xh, const unsigned short* __restrict__ xl,
    const unsigned short* __restrict__ wth, const unsigned short* __restrict__ wtl,
    const float* __restrict__ a1, const float* __restrict__ a2,
    unsigned short* __restrict__ hT, float* __restrict__ s1,
    float* __restrict__ s2)
{
    const int head = blockIdx.x & 7;
    const int rb = blockIdx.x >> 3;                  // 0..95
    const int w = threadIdx.x >> 6;
    const int lane = threadIdx.x & 63;
    const int r15 = lane & 15;
    const int g = lane >> 4;
    const int rowbase = rb * 64 + w * 16;
    const int rowA = rowbase + r15;

    f32x4 acc[4] = {};
    const unsigned short* xhp = xh + (size_t)rowA * IN_F + g * 8;
    const unsigned short* xlp = xl + (size_t)rowA * IN_F + g * 8;
    const int colbase = head * 64;

#pragma unroll 4
    for (int i = 0; i < 16; ++i) {
        const int k0 = i * 32;
        bf16x8 ah = *(const bf16x8*)(xhp + k0);
        bf16x8 al = *(const bf16x8*)(xlp + k0);
#pragma unroll
        for (int ct = 0; ct < 4; ++ct) {
            size_t boff = (size_t)(colbase + ct * 16 + r15) * IN_F + k0 + g * 8;
            bf16x8 bh = *(const bf16x8*)(wth + boff);
            bf16x8 bl = *(const bf16x8*)(wtl + boff);
            acc[ct] = MFMA16B(ah, bh, acc[ct]);
            acc[ct] = MFMA16B(ah, bl, acc[ct]);
            acc[ct] = MFMA16B(al, bh, acc[ct]);
        }
    }

    float a1v[4], a2v[4];
#pragma unroll
    for (int ct = 0; ct < 4; ++ct) {
        a1v[ct] = a1[head * 64 + ct * 16 + r15];
        a2v[ct] = a2[head * 64 + ct * 16 + r15];
    }
    float sp1[4] = {0, 0, 0, 0}, sp2[4] = {0, 0, 0, 0};
#pragma unroll
    for (int ct = 0; ct < 4; ++ct)
#pragma unroll
        for (int j = 0; j < 4; ++j) {
            sp1[j] += acc[ct][j] * a1v[ct];
            sp2[j] += acc[ct][j] * a2v[ct];
        }
#pragma unroll
    for (int d = 1; d < 16; d <<= 1) {
#pragma unroll
        for (int j = 0; j < 4; ++j) {
            sp1[j] += __shfl_xor(sp1[j], d);
            sp2[j] += __shfl_xor(sp2[j], d);
        }
    }
    if (r15 == 0) {
#pragma unroll
        for (int j = 0; j < 4; ++j) {
            int n = rowbase + g * 4 + j;
            s1[head * N_NODES + n] = sp1[j];
            s2[head * N_NODES + n] = sp2[j];
        }
    }
#pragma unroll
    for (int ct = 0; ct < 4; ++ct) {
        ushort4 pk;
        pk.x = f2bf(acc[ct][0]);
        pk.y = f2bf(acc[ct][1]);
        pk.z = f2bf(acc[ct][2]);
        pk.w = f2bf(acc[ct][3]);
        int fcol = head * 64 + ct * 16 + r15;
        int n0 = rowbase + g * 4;
        *(ushort4*)(hT + (size_t)fcol * N_NODES + n0) = pk;
    }
}

// ---------------------------------------------------------------------------
// Repack hT (bf16 [h][f][n]) -> hTF (f16, MFMA-B-fragment order):
// hTF[(((head*96 + t)*8 + wk*4 + ct)*64 + lane)*8 + e]
//   = f16( hT[head][ct*16 + (lane&15)][t*64 + wk*32 + (lane>>4)*8 + e] )
__global__ __launch_bounds__(256) void k_repack(
    const unsigned short* __restrict__ hT, unsigned short* __restrict__ hTF)
{
    int tid = blockIdx.x * 256 + threadIdx.x;        // 393216
    int lane = tid & 63;
    int rest = tid >> 6;                             // frag id
    int ct = rest & 3, wk = (rest >> 2) & 1;
    int ft = rest >> 3;
    int t = ft % 96, head = ft / 96;
    int f = ct * 16 + (lane & 15);
    int n0 = t * 64 + wk * 32 + (lane >> 4) * 8;
    const unsigned short* src = hT + (size_t)(head * 64 + f) * N_NODES + n0;
    ushort4 a = *(const ushort4*)src;
    ushort4 b = *(const ushort4*)(src + 4);
    unsigned short in[8] = {a.x, a.y, a.z, a.w, b.x, b.y, b.z, b.w};
    unsigned short o[8];
#pragma unroll
    for (int e = 0; e < 8; ++e) {
        _Float16 h = (_Float16)bf2f(in[e]);
        union { _Float16 h; unsigned short u; } c;
        c.h = h;
        o[e] = c.u;
    }
    ushort4* dst = (ushort4*)(hTF + (size_t)tid * 8);
    dst[0] = make_ushort4(o[0], o[1], o[2], o[3]);
    dst[1] = make_ushort4(o[4], o[5], o[6], o[7]);
}

// ---------------------------------------------------------------------------
// per-head max of s2 (unmasked upper bound for softmax stabilization)
__global__ __launch_bounds__(256) void k_s2max(
    const float* __restrict__ s2, float* __restrict__ s2m)
{
    const int h = blockIdx.x;
    float m = -3.0e38f;
    for (int i = threadIdx.x; i < N_NODES; i += 256)
        m = fmaxf(m, s2[h * N_NODES + i]);
#pragma unroll
    for (int d = 1; d < 64; d <<= 1) m = fmaxf(m, __shfl_xor(m, d));
    __shared__ float wm[4];
    if ((threadIdx.x & 63) == 0) wm[threadIdx.x >> 6] = m;
    __syncthreads();
    if (threadIdx.x == 0)
        s2m[h] = fmaxf(fmaxf(wm[0], wm[1]), fmaxf(wm[2], wm[3]));
}

// ---------------------------------------------------------------------------
// packed-f16 tables: epq[i] = {f16 exp(s2[2i]-s2m), f16 exp(s2[2i+1]-s2m)},
// enq same with alpha scaling. All values <= 1.
__global__ __launch_bounds__(256) void k_tables(
    const float* __restrict__ s2, const float* __restrict__ s2m,
    uint32_t* __restrict__ epq, uint32_t* __restrict__ enq)
{
    int i = blockIdx.x * 256 + threadIdx.x;          // H*N/2
    int h = (2 * i) / N_NODES;
    float sm = s2m[h];
    float v0 = s2[2 * i] - sm, v1 = s2[2 * i + 1] - sm;
    uint32_t p0 = f16bits((_Float16)exp2f(v0 * L2E));
    uint32_t p1 = f16bits((_Float16)exp2f(v1 * L2E));
    uint32_t n0 = f16bits((_Float16)exp2f(ALPHA * v0 * L2E));
    uint32_t n1 = f16bits((_Float16)exp2f(ALPHA * v1 * L2E));
    epq[i] = p0 | (p1 << 16);
    enq[i] = n0 | (n1 << 16);
}

// ---------------------------------------------------------------------------
// packed-f16 P fragment: per m-pair j: p2 = max(E1p2*ep2, E1n2*en2) & maskbits
__device__ __forceinline__ f16x8 mk_pa16(int4 ep, int4 en, uint32_t e1p2,
                                         uint32_t e1n2, uint32_t ms)
{
    const uint32_t epw[4] = {(uint32_t)ep.x, (uint32_t)ep.y, (uint32_t)ep.z,
                             (uint32_t)ep.w};
    const uint32_t enw[4] = {(uint32_t)en.x, (uint32_t)en.y, (uint32_t)en.z,
                             (uint32_t)en.w};
    union { uint32_t u[4]; f16x8 v; } r;
#pragma unroll
    for (int j = 0; j < 4; ++j) {
        uint32_t pa, pb, pm;
        asm("v_pk_mul_f16 %0, %1, %2" : "=v"(pa) : "v"(e1p2), "v"(epw[j]));
        asm("v_pk_mul_f16 %0, %1, %2" : "=v"(pb) : "v"(e1n2), "v"(enw[j]));
        asm("v_pk_max_f16 %0, %1, %2" : "=v"(pm) : "v"(pa), "v"(pb));
        uint32_t msk = (((ms >> (2 * j)) & 1u) ? 0x0000FFFFu : 0u) |
                       (((ms >> (2 * j + 1)) & 1u) ? 0xFFFF0000u : 0u);
        r.u[j] = pm & msk;
    }
    return r.v;
}

struct Pf {                          // one-tile-ahead register prefetch
    int4 hb0, hb1, hb2, hb3;         // 4 H B-fragments (f16, this wave's kk)
    int4 ep, en;                     // packed-f16 tables (8 m)
    uint32_t m0, m1;                 // adjacency mask words per row-group
};

__device__ __forceinline__ f16x8 as_f16x8(int4 v) {
    union { int4 i; f16x8 h; } c;
    c.i = v;
    return c.h;
}

// ---------------------------------------------------------------------------
// Flash attention v5: barrier-free, LDS-free main loop. 4 waves/block, each
// wave = (row-half w01, m-half wk) fully independent: H fragments read
// directly from L2 (fragment-ordered hTF, coalesced int4), packed-f16 score
// math (pk_mul/pk_max), f16 MFMA. One-tile-ahead register prefetch. LDS used
// only for the wk-pair combine epilogue.
__global__ __launch_bounds__(256, 3) void k_flash(
    const unsigned short* __restrict__ hTF, const float* __restrict__ s1,
    const float* __restrict__ s2m, const uint32_t* __restrict__ epq,
    const uint32_t* __restrict__ enq, const uint32_t* __restrict__ bmT32,
    float* __restrict__ out)
{
    __shared__ float fs[128 * 20];                   // 10 KB epilogue scratch

    const int head = blockIdx.x / NTILES;
    const int rb = blockIdx.x % NTILES;
    const int tid = threadIdx.x;
    const int w = tid >> 6, lane = tid & 63, r15 = lane & 15, g = lane >> 4;
    const int w01 = w & 1;                           // row half
    const int wk = w >> 1;                           // m half (kk)
    const int shg = g * 8;                           // mask bit offset

    const int rA = rb * 64 + w01 * 32 + r15;
    const int rB = rA + 16;
    const float s2mh = s2m[head];
    const float s1A = s1[head * N_NODES + rA];
    const float s1B = s1[head * N_NODES + rB];
    const float t0A = s1A + s2mh, t0B = s1B + s2mh;
    const float MrA = fmaxf(t0A, ALPHA * t0A);
    const float MrB = fmaxf(t0B, ALPHA * t0B);
    // packed-f16 row constants (broadcast to both halves)
    uint32_t E1pA2, E1nA2, E1pB2, E1nB2;
    {
        uint32_t a = f16bits((_Float16)exp2f((t0A - MrA) * L2E));
        uint32_t b = f16bits((_Float16)exp2f((ALPHA * t0A - MrA) * L2E));
        uint32_t c = f16bits((_Float16)exp2f((t0B - MrB) * L2E));
        uint32_t d = f16bits((_Float16)exp2f((ALPHA * t0B - MrB) * L2E));
        E1pA2 = a | (a << 16);
        E1nA2 = b | (b << 16);
        E1pB2 = c | (c << 16);
        E1nB2 = d | (d << 16);
    }

    // fragment-ordered H pointer: frag stride per tile = 8*512 shorts
    const unsigned short* __restrict__ hbp =
        hTF + ((size_t)(head * 96) * 8 + wk * 4) * 512 + lane * 8;
    const uint32_t* __restrict__ epb = epq + head * 3072 + wk * 16 + g * 4;
    const uint32_t* __restrict__ enb = enq + head * 3072 + wk * 16 + g * 4;
    const size_t mbA = (size_t)rA * 2 + wk;          // + t*12288 per tile
    const size_t mbB = (size_t)rB * 2 + wk;

    f32x4 accA[4] = {}, accB[4] = {};
    f32x4 accSA = {}, accSB = {};
    const f16x8 vones = {(_Float16)1.0f, (_Float16)1.0f, (_Float16)1.0f,
                         (_Float16)1.0f, (_Float16)1.0f, (_Float16)1.0f,
                         (_Float16)1.0f, (_Float16)1.0f};

    auto loadPf = [&](int t, Pf& P) {
        const unsigned short* hp = hbp + (size_t)t * 4096;
        P.hb0 = *(const int4*)(hp);
        P.hb1 = *(const int4*)(hp + 512);
        P.hb2 = *(const int4*)(hp + 1024);
        P.hb3 = *(const int4*)(hp + 1536);
        P.ep = *(const int4*)(epb + t * 32);
        P.en = *(const int4*)(enb + t * 32);
        P.m0 = bmT32[mbA + (size_t)t * 12288];
        P.m1 = bmT32[mbB + (size_t)t * 12288];
    };
    auto compute = [&](Pf& C) {
        f16x8 paA = mk_pa16(C.ep, C.en, E1pA2, E1nA2, C.m0 >> shg);
        f16x8 paB = mk_pa16(C.ep, C.en, E1pB2, E1nB2, C.m1 >> shg);
        accSA = MFMA16H(paA, vones, accSA);
        accSB = MFMA16H(paB, vones, accSB);
        f16x8 h0 = as_f16x8(C.hb0), h1 = as_f16x8(C.hb1);
        f16x8 h2 = as_f16x8(C.hb2), h3 = as_f16x8(C.hb3);
        accA[0] = MFMA16H(paA, h0, accA[0]);
        accB[0] = MFMA16H(paB, h0, accB[0]);
        accA[1] = MFMA16H(paA, h1, accA[1]);
        accB[1] = MFMA16H(paB, h1, accB[1]);
        accA[2] = MFMA16H(paA, h2, accA[2]);
        accB[2] = MFMA16H(paB, h2, accB[2]);
        accA[3] = MFMA16H(paA, h3, accA[3]);
        accB[3] = MFMA16H(paB, h3, accB[3]);
    };

    Pf A, B;
    loadPf(0, A);
    for (int t = 0; t < NTILES; t += 2) {
        loadPf(t + 1, B);                            // NTILES even: always valid
        compute(A);
        if (t + 2 < NTILES) loadPf(t + 2, A);
        compute(B);
    }

    // ---- epilogue: combine the two m-half waves through LDS ----
    const int slot = w01 * 64 + lane;
    const int fcb = head * 64;
    const int nA = rb * 64 + w01 * 32 + g * 4;

    // phase 1: row-group A
    if (wk == 1) {
#pragma unroll
        for (int ct = 0; ct < 4; ++ct)
#pragma unroll
            for (int j = 0; j < 4; ++j) fs[slot * 20 + ct * 4 + j] = accA[ct][j];
#pragma unroll
        for (int j = 0; j < 4; ++j) fs[slot * 20 + 16 + j] = accSA[j];
    }
    __syncthreads();
    if (wk == 0) {
        float rinv[4];
#pragma unroll
        for (int j = 0; j < 4; ++j)
            rinv[j] = 1.0f / (accSA[j] + fs[slot * 20 + 16 + j]);
#pragma unroll
        for (int ct = 0; ct < 4; ++ct)
#pragma unroll
            for (int j = 0; j < 4; ++j) {
                float v = (accA[ct][j] + fs[slot * 20 + ct * 4 + j]) * rinv[j];
                v = (v > 0.f) ? v : (expf(v) - 1.f);
                out[(size_t)(nA + j) * 512 + fcb + ct * 16 + r15] = v;
            }
    }
    __syncthreads();
    // phase 2: row-group B
    if (wk == 1) {
#pragma unroll
        for (int ct = 0; ct < 4; ++ct)
#pragma unroll
            for (int j = 0; j < 4; ++j) fs[slot * 20 + ct * 4 + j] = accB[ct][j];
#pragma unroll
        for (int j = 0; j < 4; ++j) fs[slot * 20 + 16 + j] = accSB[j];
    }
    __syncthreads();
    if (wk == 0) {
        float rinv[4];
#pragma unroll
        for (int j = 0; j < 4; ++j)
            rinv[j] = 1.0f / (accSB[j] + fs[slot * 20 + 16 + j]);
#pragma unroll
        for (int ct = 0; ct < 4; ++ct)
#pragma unroll
            for (int j = 0; j < 4; ++j) {
                float v = (accB[ct][j] + fs[slot * 20 + ct * 4 + j]) * rinv[j];
                v = (v > 0.f) ? v : (expf(v) - 1.f);
                out[(size_t)(nA + 16 + j) * 512 + fcb + ct * 16 + r15] = v;
            }
    }
}

// ---------------------------------------------------------------------------
extern "C" void kernel_launch(void* const* d_in, const int* in_sizes, int n_in,
                              void* d_out, int out_size, void* d_ws, size_t ws_size,
                              hipStream_t stream)
{
    const float* x = (const float*)d_in[0];
    const int* adj = (const int*)d_in[1];
    const float* W = (const float*)d_in[2];
    const float* a1 = (const float*)d_in[3];
    const float* a2 = (const float*)d_in[4];
    float* out = (float*)d_out;

    char* ws = (char*)d_ws;
    size_t off = 0;
    auto take = [&](size_t bytes) {
        void* p = ws + off;
        off = (off + bytes + 255) & ~(size_t)255;
        return p;
    };
    unsigned short* xh  = (unsigned short*)take((size_t)N_NODES * IN_F * 2);
    unsigned short* xl  = (unsigned short*)take((size_t)N_NODES * IN_F * 2);
    unsigned short* wth = (unsigned short*)take((size_t)512 * 512 * 2);
    unsigned short* wtl = (unsigned short*)take((size_t)512 * 512 * 2);
    unsigned short* hT  = (unsigned short*)take((size_t)NH * 64 * N_NODES * 2);
    unsigned short* hTF = (unsigned short*)take((size_t)NH * 64 * N_NODES * 2);
    float* s1  = (float*)take((size_t)NH * N_NODES * 4);
    float* s2  = (float*)take((size_t)NH * N_NODES * 4);
    float* s2m = (float*)take(256);
    uint32_t* epq = (uint32_t*)take((size_t)NH * N_NODES / 2 * 4);
    uint32_t* enq = (uint32_t*)take((size_t)NH * N_NODES / 2 * 4);
    unsigned long long* bmT =
        (unsigned long long*)take((size_t)N_NODES * (N_NODES / 64) * 8);

    k_convert_x<<<dim3((N_NODES * IN_F / 4) / 256), dim3(256), 0, stream>>>(x, xh, xl);
    k_convert_w<<<dim3((512 * 512) / 256), dim3(256), 0, stream>>>(W, wth, wtl);
    k_pack_adj<<<dim3(2048), dim3(256), 0, stream>>>(adj, bmT);
    k_proj<<<dim3(NH * (N_NODES / 64)), dim3(256), 0, stream>>>(
        xh, xl, wth, wtl, a1, a2, hT, s1, s2);
    k_repack<<<dim3(1536), dim3(256), 0, stream>>>(hT, hTF);
    k_s2max<<<dim3(NH), dim3(256), 0, stream>>>(s2, s2m);
    k_tables<<<dim3(NH * N_NODES / 2 / 256), dim3(256), 0, stream>>>(
        s2, s2m, epq, enq);
    k_flash<<<dim3(NH * NTILES), dim3(256), 0, stream>>>(
        hTF, s1, s2m, epq, enq, (const uint32_t*)bmT, out);
}